// Round 2
// baseline (1209.636 us; speedup 1.0000x reference)
//
#include <hip/hip_runtime.h>
#include <hip/hip_bf16.h>

#define IN_CH 128
#define HID 32
#define OUT_CH 16
#define SCAN_CHUNK 1024

// ---------------------------------------------------------------------------
// dtype sniffing: edge_index is int64 per the reference but may arrive int32.
// int32 data read as int64 gives >= 2^32 w.p. ~1-1e-5 per sample; 64 samples.
// ---------------------------------------------------------------------------
__global__ void detect_dtype(const void* ei, long long ecount, int n, int* flag) {
    if (threadIdx.x == 0 && blockIdx.x == 0) {
        int is64 = 1;
        const long long* p = (const long long*)ei;
        long long st = ecount / 64; if (st < 1) st = 1;
        for (int j = 0; j < 64; ++j) {
            long long idx = (long long)j * st;
            if (idx >= ecount) break;
            long long v = p[idx];
            if (v < 0 || v >= n) { is64 = 0; break; }
        }
        *flag = is64;
    }
}

__device__ __forceinline__ int load_idx(const void* ei, long long i, int is64) {
    return is64 ? (int)((const long long*)ei)[i] : ((const int*)ei)[i];
}

// ---------------------------------------------------------------------------
__global__ __launch_bounds__(256) void zero_int(int* p, int n) {
    int i = blockIdx.x * 256 + threadIdx.x;
    if (i < n) p[i] = 0;
}

__global__ __launch_bounds__(256) void zero_float(float* p, long long n) {
    long long i = (long long)blockIdx.x * 256 + threadIdx.x;
    if (i < n) p[i] = 0.f;
}

__global__ __launch_bounds__(256) void count_edges(const void* ei, int* cnt,
                                                   long long ecount, const int* flag) {
    long long e = (long long)blockIdx.x * 256 + threadIdx.x;
    if (e >= ecount) return;
    int is64 = *flag;
    int col = load_idx(ei, ecount + e, is64);
    atomicAdd(&cnt[col], 1);
}

__global__ __launch_bounds__(256) void compute_dinv(const int* cnt, float* dinv, int n) {
    int i = blockIdx.x * 256 + threadIdx.x;
    if (i < n) dinv[i] = 1.0f / sqrtf((float)(cnt[i] + 1));  // +1 self loop
}

// ---------------------------------------------------------------------------
// exclusive scan (3-phase) over cnt -> offs
// ---------------------------------------------------------------------------
__global__ __launch_bounds__(256) void scan_partial(const int* cnt, int* partial, int n) {
    __shared__ int sd[256];
    int base = blockIdx.x * SCAN_CHUNK;
    int s = 0;
    for (int j = threadIdx.x; j < SCAN_CHUNK; j += 256) {
        int i = base + j;
        if (i < n) s += cnt[i];
    }
    sd[threadIdx.x] = s;
    __syncthreads();
    for (int off = 128; off > 0; off >>= 1) {
        if (threadIdx.x < off) sd[threadIdx.x] += sd[threadIdx.x + off];
        __syncthreads();
    }
    if (threadIdx.x == 0) partial[blockIdx.x] = sd[0];
}

__global__ void scan_serial(int* partial, int* offs, int nblk, int n) {
    if (threadIdx.x == 0 && blockIdx.x == 0) {
        int run = 0;
        for (int b = 0; b < nblk; ++b) { int t = partial[b]; partial[b] = run; run += t; }
        offs[n] = run;
    }
}

__global__ __launch_bounds__(256) void scan_final(const int* cnt, const int* partial,
                                                  int* offs, int n) {
    __shared__ int sd[256];
    int base = blockIdx.x * SCAN_CHUNK;
    int t = threadIdx.x;
    int loc[4]; int ts = 0;
#pragma unroll
    for (int j = 0; j < 4; ++j) {
        int i = base + t * 4 + j;
        loc[j] = (i < n) ? cnt[i] : 0;
        ts += loc[j];
    }
    sd[t] = ts;
    __syncthreads();
    for (int off = 1; off < 256; off <<= 1) {
        int v = (t >= off) ? sd[t - off] : 0;
        __syncthreads();
        sd[t] += v;
        __syncthreads();
    }
    int excl = sd[t] - ts + partial[blockIdx.x];
#pragma unroll
    for (int j = 0; j < 4; ++j) {
        int i = base + t * 4 + j;
        if (i < n) offs[i] = excl;
        excl += loc[j];
    }
}

__global__ __launch_bounds__(256) void copy_int(const int* src, int* dst, int n) {
    int i = blockIdx.x * 256 + threadIdx.x;
    if (i < n) dst[i] = src[i];
}

__global__ __launch_bounds__(256) void fill_csr(const void* ei, int* cursor, int* csr,
                                                long long ecount, const int* flag) {
    long long e = (long long)blockIdx.x * 256 + threadIdx.x;
    if (e >= ecount) return;
    int is64 = *flag;
    int row = load_idx(ei, e, is64);
    int col = load_idx(ei, ecount + e, is64);
    int pos = atomicAdd(&cursor[col], 1);
    csr[pos] = row;
}

// ---------------------------------------------------------------------------
// layer GEMMs (tiny: vector-FP32; no fp32-input MFMA on CDNA4)
// ---------------------------------------------------------------------------
__global__ __launch_bounds__(256) void gemm1(const float* __restrict__ x,
                                             const float* __restrict__ W1,
                                             float* __restrict__ m1,
                                             __hip_bfloat16* __restrict__ m1b,
                                             int n, int bf16out) {
    __shared__ float sW[IN_CH * HID];     // 16 KB
    __shared__ float sx[8][IN_CH];        // 4 KB
    for (int i = threadIdx.x; i < IN_CH * HID; i += 256) sW[i] = W1[i];
    int g = threadIdx.x >> 5;
    int c = threadIdx.x & 31;
    long long node = (long long)blockIdx.x * 8 + g;
    bool active = node < n;
    if (active) {
        const float4* xr = (const float4*)(x + node * IN_CH);
        float4 v = xr[c];
        sx[g][c * 4 + 0] = v.x; sx[g][c * 4 + 1] = v.y;
        sx[g][c * 4 + 2] = v.z; sx[g][c * 4 + 3] = v.w;
    }
    __syncthreads();
    if (!active) return;
    float acc = 0.f;
#pragma unroll
    for (int k = 0; k < IN_CH; ++k)
        acc = fmaf(sx[g][k], sW[k * HID + c], acc);
    if (bf16out) m1b[node * HID + c] = __float2bfloat16(acc);
    else         m1[node * HID + c] = acc;
}

__global__ __launch_bounds__(256) void gemm2(const float* __restrict__ h,
                                             const float* __restrict__ W2,
                                             float* __restrict__ m2, int n) {
    __shared__ float sW[HID * OUT_CH];    // 512 floats — MUST strided-load (256 thr)
    for (int i = threadIdx.x; i < HID * OUT_CH; i += 256) sW[i] = W2[i];
    __syncthreads();
    long long t = (long long)blockIdx.x * 256 + threadIdx.x;
    long long node = t >> 4;
    int c = (int)(t & 15);
    if (node >= n) return;
    const float* hr = h + node * HID;
    float acc = 0.f;
#pragma unroll
    for (int k = 0; k < HID; ++k)
        acc = fmaf(hr[k], sW[k * OUT_CH + c], acc);
    m2[node * OUT_CH + c] = acc;
}

// ---------------------------------------------------------------------------
// Tier 1: gather aggregation (CSR), no float atomics
// ---------------------------------------------------------------------------
__global__ __launch_bounds__(256) void agg1(const float* __restrict__ m1,
                                            const int* __restrict__ csr,
                                            const int* __restrict__ offs,
                                            const float* __restrict__ dinv,
                                            const float* __restrict__ b1,
                                            float* __restrict__ h, int n) {
    int g = threadIdx.x >> 5;
    int c = threadIdx.x & 31;
    long long node = (long long)blockIdx.x * 8 + g;
    if (node >= n) return;
    float di = dinv[node];
    float acc = m1[node * HID + c] * di;   // self loop (second di applied at end)
    int s = offs[node], epos = offs[node + 1];
    for (; s + 1 < epos; s += 2) {
        int s0 = csr[s], s1 = csr[s + 1];
        float f0 = dinv[s0], f1 = dinv[s1];
        acc = fmaf(m1[(long long)s0 * HID + c], f0, acc);
        acc = fmaf(m1[(long long)s1 * HID + c], f1, acc);
    }
    if (s < epos) {
        int s0 = csr[s];
        acc = fmaf(m1[(long long)s0 * HID + c], dinv[s0], acc);
    }
    float v = acc * di + b1[c];
    h[node * HID + c] = v > 0.f ? v : 0.f;
}

__global__ __launch_bounds__(256) void agg2(const float* __restrict__ m2,
                                            const int* __restrict__ csr,
                                            const int* __restrict__ offs,
                                            const float* __restrict__ dinv,
                                            const float* __restrict__ b2,
                                            float* __restrict__ out, int n) {
    int g = threadIdx.x >> 4;
    int c = threadIdx.x & 15;
    long long node = (long long)blockIdx.x * 16 + g;
    if (node >= n) return;
    float di = dinv[node];
    float acc = m2[node * OUT_CH + c] * di;
    int s = offs[node], epos = offs[node + 1];
    for (; s + 1 < epos; s += 2) {
        int s0 = csr[s], s1 = csr[s + 1];
        float f0 = dinv[s0], f1 = dinv[s1];
        acc = fmaf(m2[(long long)s0 * OUT_CH + c], f0, acc);
        acc = fmaf(m2[(long long)s1 * OUT_CH + c], f1, acc);
    }
    if (s < epos) {
        int s0 = csr[s];
        acc = fmaf(m2[(long long)s0 * OUT_CH + c], dinv[s0], acc);
    }
    out[node * OUT_CH + c] = acc * di + b2[c];
}

// ---------------------------------------------------------------------------
// Tier 2/3: atomic scatter fallback (small workspace)
// ---------------------------------------------------------------------------
template <int BSRC>
__global__ __launch_bounds__(256) void scatter1(const float* __restrict__ m1,
                                                const __hip_bfloat16* __restrict__ m1b,
                                                const void* ei, const float* __restrict__ dinv,
                                                float* __restrict__ h,
                                                long long ecount, const int* flag) {
    long long e = (long long)blockIdx.x * 8 + (threadIdx.x >> 5);
    int c = threadIdx.x & 31;
    if (e >= ecount) return;
    int is64 = *flag;
    int row = load_idx(ei, e, is64);
    int col = load_idx(ei, ecount + e, is64);
    float nrm = dinv[row] * dinv[col];
    float v = BSRC ? __bfloat162float(m1b[(long long)row * HID + c])
                   : m1[(long long)row * HID + c];
    atomicAdd(&h[(long long)col * HID + c], v * nrm);
}

template <int BSRC>
__global__ __launch_bounds__(256) void fixup1(const float* __restrict__ m1,
                                              const __hip_bfloat16* __restrict__ m1b,
                                              const float* __restrict__ dinv,
                                              const float* __restrict__ b1,
                                              float* __restrict__ h, int n) {
    long long t = (long long)blockIdx.x * 256 + threadIdx.x;
    long long node = t >> 5; int c = (int)(t & 31);
    if (node >= n) return;
    float di = dinv[node];
    float self = BSRC ? __bfloat162float(m1b[node * HID + c]) : m1[node * HID + c];
    float v = h[node * HID + c] + self * di * di + b1[c];
    h[node * HID + c] = v > 0.f ? v : 0.f;
}

__global__ __launch_bounds__(256) void scatter2(const float* __restrict__ m2, const void* ei,
                                                const float* __restrict__ dinv,
                                                float* __restrict__ out,
                                                long long ecount, const int* flag) {
    long long e = (long long)blockIdx.x * 16 + (threadIdx.x >> 4);
    int c = threadIdx.x & 15;
    if (e >= ecount) return;
    int is64 = *flag;
    int row = load_idx(ei, e, is64);
    int col = load_idx(ei, ecount + e, is64);
    float nrm = dinv[row] * dinv[col];
    atomicAdd(&out[(long long)col * OUT_CH + c], m2[(long long)row * OUT_CH + c] * nrm);
}

__global__ __launch_bounds__(256) void fixup2(const float* __restrict__ m2,
                                              const float* __restrict__ dinv,
                                              const float* __restrict__ b2,
                                              float* __restrict__ out, int n) {
    long long t = (long long)blockIdx.x * 256 + threadIdx.x;
    long long node = t >> 4; int c = (int)(t & 15);
    if (node >= n) return;
    float di = dinv[node];
    out[node * OUT_CH + c] += m2[node * OUT_CH + c] * di * di + b2[c];
}

// ---------------------------------------------------------------------------
extern "C" void kernel_launch(void* const* d_in, const int* in_sizes, int n_in,
                              void* d_out, int out_size, void* d_ws, size_t ws_size,
                              hipStream_t stream) {
    const float* x  = (const float*)d_in[0];
    const void*  ei = d_in[1];
    const float* W1 = (const float*)d_in[2];
    const float* b1 = (const float*)d_in[3];
    const float* W2 = (const float*)d_in[4];
    const float* b2 = (const float*)d_in[5];
    float* out = (float*)d_out;

    const int n = in_sizes[0] / IN_CH;           // 100000
    const long long E = in_sizes[1] / 2;         // 6400000

    char* w = (char*)d_ws;
    size_t used = 0;
    auto carve = [&](size_t bytes) -> void* {
        void* p = (void*)(w + used);
        used += (bytes + 255) & ~(size_t)255;
        return p;
    };
    auto A = [](size_t b) -> size_t { return (b + 255) & ~(size_t)255; };

    int*   cnt     = (int*)carve((size_t)n * 4);          // degree counts, later cursor
    int*   offs    = (int*)carve((size_t)(n + 1) * 4);
    float* dinv    = (float*)carve((size_t)n * 4);
    int*   partial = (int*)carve(4096);
    int*   flag    = (int*)carve(256);
    const size_t base = used;

    const size_t needT1 = base + A((size_t)E * 4) + A((size_t)n * HID * 4) + A((size_t)n * HID * 4);
    const size_t needT2 = base + A((size_t)n * HID * 4) + A((size_t)n * HID * 4);
    const int tier = (ws_size >= needT1) ? 1 : ((ws_size >= needT2) ? 2 : 3);

    const int nblkN  = (n + 255) / 256;
    const int nblkE  = (int)((E + 255) / 256);
    const int nblkSc = (n + SCAN_CHUNK - 1) / SCAN_CHUNK;
    const int nblkH  = (int)(((long long)n * HID + 255) / 256);
    const int nblkO  = (int)(((long long)n * OUT_CH + 255) / 256);

    detect_dtype<<<1, 64, 0, stream>>>(ei, E, n, flag);
    zero_int<<<nblkN, 256, 0, stream>>>(cnt, n);
    count_edges<<<nblkE, 256, 0, stream>>>(ei, cnt, E, flag);
    compute_dinv<<<nblkN, 256, 0, stream>>>(cnt, dinv, n);

    if (tier == 1) {
        int*   csr = (int*)carve((size_t)E * 4);
        float* m1  = (float*)carve((size_t)n * HID * 4);
        float* h   = (float*)carve((size_t)n * HID * 4);
        float* m2  = m1;   // m1 dead after agg1; reuse for m2

        scan_partial<<<nblkSc, 256, 0, stream>>>(cnt, partial, n);
        scan_serial<<<1, 64, 0, stream>>>(partial, offs, nblkSc, n);
        scan_final<<<nblkSc, 256, 0, stream>>>(cnt, partial, offs, n);
        copy_int<<<nblkN, 256, 0, stream>>>(offs, cnt, n);      // cnt becomes cursor
        fill_csr<<<nblkE, 256, 0, stream>>>(ei, cnt, csr, E, flag);

        gemm1<<<(n + 7) / 8, 256, 0, stream>>>(x, W1, m1, (__hip_bfloat16*)nullptr, n, 0);
        agg1<<<(n + 7) / 8, 256, 0, stream>>>(m1, csr, offs, dinv, b1, h, n);
        gemm2<<<nblkO, 256, 0, stream>>>(h, W2, m2, n);
        agg2<<<(n + 15) / 16, 256, 0, stream>>>(m2, csr, offs, dinv, b2, out, n);
    } else if (tier == 2) {
        float* m1 = (float*)carve((size_t)n * HID * 4);
        float* h  = (float*)carve((size_t)n * HID * 4);
        float* m2 = m1;

        gemm1<<<(n + 7) / 8, 256, 0, stream>>>(x, W1, m1, (__hip_bfloat16*)nullptr, n, 0);
        zero_float<<<nblkH, 256, 0, stream>>>(h, (long long)n * HID);
        scatter1<0><<<(int)((E + 7) / 8), 256, 0, stream>>>(m1, nullptr, ei, dinv, h, E, flag);
        fixup1<0><<<nblkH, 256, 0, stream>>>(m1, nullptr, dinv, b1, h, n);
        gemm2<<<nblkO, 256, 0, stream>>>(h, W2, m2, n);
        zero_float<<<nblkO, 256, 0, stream>>>(out, (long long)n * OUT_CH);
        scatter2<<<(int)((E + 15) / 16), 256, 0, stream>>>(m2, ei, dinv, out, E, flag);
        fixup2<<<nblkO, 256, 0, stream>>>(m2, dinv, b2, out, n);
    } else {
        __hip_bfloat16* m1b = (__hip_bfloat16*)carve((size_t)n * HID * 2);
        float* h  = (float*)carve((size_t)n * HID * 4);
        float* m2 = (float*)m1b;   // n*16*4 == n*32*2 bytes; m1b dead after fixup1

        gemm1<<<(n + 7) / 8, 256, 0, stream>>>(x, W1, (float*)nullptr, m1b, n, 1);
        zero_float<<<nblkH, 256, 0, stream>>>(h, (long long)n * HID);
        scatter1<1><<<(int)((E + 7) / 8), 256, 0, stream>>>(nullptr, m1b, ei, dinv, h, E, flag);
        fixup1<1><<<nblkH, 256, 0, stream>>>(nullptr, m1b, dinv, b1, h, n);
        gemm2<<<nblkO, 256, 0, stream>>>(h, W2, m2, n);
        zero_float<<<nblkO, 256, 0, stream>>>(out, (long long)n * OUT_CH);
        scatter2<<<(int)((E + 15) / 16), 256, 0, stream>>>(m2, ei, dinv, out, E, flag);
        fixup2<<<nblkO, 256, 0, stream>>>(m2, dinv, b2, out, n);
    }
}

// Round 3
// 976.725 us; speedup vs baseline: 1.2385x; 1.2385x over previous
//
#include <hip/hip_runtime.h>
#include <hip/hip_bf16.h>

#define IN_CH 128
#define HID 32
#define OUT_CH 16
#define SCAN_CHUNK 1024
#define FILL_K 12        // csr write-window count: 25.6MB/12 ~ 2.1MB, L2-resident
#define EPT 4            // edges per thread in edge-scan kernels

// ---------------------------------------------------------------------------
// dtype sniffing: edge_index is int64 per the reference but may arrive int32.
// ---------------------------------------------------------------------------
__global__ void detect_dtype(const void* ei, long long ecount, int n, int* flag) {
    if (threadIdx.x == 0 && blockIdx.x == 0) {
        int is64 = 1;
        const long long* p = (const long long*)ei;
        long long st = ecount / 64; if (st < 1) st = 1;
        for (int j = 0; j < 64; ++j) {
            long long idx = (long long)j * st;
            if (idx >= ecount) break;
            long long v = p[idx];
            if (v < 0 || v >= n) { is64 = 0; break; }
        }
        *flag = is64;
    }
}

__device__ __forceinline__ int load_idx(const void* ei, long long i, int is64) {
    return is64 ? (int)((const long long*)ei)[i] : ((const int*)ei)[i];
}

// load 4 consecutive edge indices starting at element base+e0 (e0 % 4 == 0)
__device__ __forceinline__ void load_idx4(const void* ei, long long off, int is64,
                                          int* c) {
    if (is64) {
        const long long* p = (const long long*)ei + off;
        c[0] = (int)p[0]; c[1] = (int)p[1]; c[2] = (int)p[2]; c[3] = (int)p[3];
    } else {
        int4 v = *(const int4*)((const int*)ei + off);
        c[0] = v.x; c[1] = v.y; c[2] = v.z; c[3] = v.w;
    }
}

// ---------------------------------------------------------------------------
__global__ __launch_bounds__(256) void zero_int(int* p, int n) {
    int i = blockIdx.x * 256 + threadIdx.x;
    if (i < n) p[i] = 0;
}

__global__ __launch_bounds__(256) void zero_float(float* p, long long n) {
    long long i = (long long)blockIdx.x * 256 + threadIdx.x;
    if (i < n) p[i] = 0.f;
}

__global__ __launch_bounds__(256) void count_edges(const void* ei, int* cnt,
                                                   long long E, const int* flag) {
    long long e0 = ((long long)blockIdx.x * 256 + threadIdx.x) * EPT;
    if (e0 >= E) return;
    int is64 = *flag;
    if (e0 + EPT <= E) {
        int c[EPT];
        load_idx4(ei, E + e0, is64, c);
#pragma unroll
        for (int j = 0; j < EPT; ++j) atomicAdd(&cnt[c[j]], 1);
    } else {
        for (long long e = e0; e < E; ++e)
            atomicAdd(&cnt[load_idx(ei, E + e, is64)], 1);
    }
}

__global__ __launch_bounds__(256) void compute_dinv(const int* cnt, float* dinv, int n) {
    int i = blockIdx.x * 256 + threadIdx.x;
    if (i < n) dinv[i] = 1.0f / sqrtf((float)(cnt[i] + 1));  // +1 self loop
}

// ---------------------------------------------------------------------------
// exclusive scan (3-phase) over cnt -> offs
// ---------------------------------------------------------------------------
__global__ __launch_bounds__(256) void scan_partial(const int* cnt, int* partial, int n) {
    __shared__ int sd[256];
    int base = blockIdx.x * SCAN_CHUNK;
    int s = 0;
    for (int j = threadIdx.x; j < SCAN_CHUNK; j += 256) {
        int i = base + j;
        if (i < n) s += cnt[i];
    }
    sd[threadIdx.x] = s;
    __syncthreads();
    for (int off = 128; off > 0; off >>= 1) {
        if (threadIdx.x < off) sd[threadIdx.x] += sd[threadIdx.x + off];
        __syncthreads();
    }
    if (threadIdx.x == 0) partial[blockIdx.x] = sd[0];
}

__global__ void scan_serial(int* partial, int* offs, int nblk, int n) {
    if (threadIdx.x == 0 && blockIdx.x == 0) {
        int run = 0;
        for (int b = 0; b < nblk; ++b) { int t = partial[b]; partial[b] = run; run += t; }
        offs[n] = run;
    }
}

__global__ __launch_bounds__(256) void scan_final(const int* cnt, const int* partial,
                                                  int* offs, int n) {
    __shared__ int sd[256];
    int base = blockIdx.x * SCAN_CHUNK;
    int t = threadIdx.x;
    int loc[4]; int ts = 0;
#pragma unroll
    for (int j = 0; j < 4; ++j) {
        int i = base + t * 4 + j;
        loc[j] = (i < n) ? cnt[i] : 0;
        ts += loc[j];
    }
    sd[t] = ts;
    __syncthreads();
    for (int off = 1; off < 256; off <<= 1) {
        int v = (t >= off) ? sd[t - off] : 0;
        __syncthreads();
        sd[t] += v;
        __syncthreads();
    }
    int excl = sd[t] - ts + partial[blockIdx.x];
#pragma unroll
    for (int j = 0; j < 4; ++j) {
        int i = base + t * 4 + j;
        if (i < n) offs[i] = excl;
        excl += loc[j];
    }
}

__global__ __launch_bounds__(256) void copy_int(const int* src, int* dst, int n) {
    int i = blockIdx.x * 256 + threadIdx.x;
    if (i < n) dst[i] = src[i];
}

// ---------------------------------------------------------------------------
// windowed CSR fill: blocks are window-major; window w only emits writes for
// cols in [w*npw, (w+1)*npw) -> csr write region ~2.1MB stays L2-resident, so
// the 16 writes/line coalesce before writeback (kills 15x write amplification)
// ---------------------------------------------------------------------------
__global__ __launch_bounds__(256) void fill_csr_win(const void* ei, int* cursor, int* csr,
                                                    long long E, const int* flag,
                                                    int blocksPerPass, int npw, int n) {
    int w = blockIdx.x / blocksPerPass;
    int b = blockIdx.x % blocksPerPass;
    int lo = w * npw;
    int hi = lo + npw; if (hi > n) hi = n;
    long long e0 = ((long long)b * 256 + threadIdx.x) * EPT;
    if (e0 >= E) return;
    int is64 = *flag;
    if (e0 + EPT <= E) {
        int c[EPT];
        load_idx4(ei, E + e0, is64, c);
#pragma unroll
        for (int j = 0; j < EPT; ++j) {
            if (c[j] >= lo && c[j] < hi) {
                int row = load_idx(ei, e0 + j, is64);
                int pos = atomicAdd(&cursor[c[j]], 1);
                csr[pos] = row;
            }
        }
    } else {
        for (long long e = e0; e < E; ++e) {
            int col = load_idx(ei, E + e, is64);
            if (col >= lo && col < hi) {
                int row = load_idx(ei, e, is64);
                int pos = atomicAdd(&cursor[col], 1);
                csr[pos] = row;
            }
        }
    }
}

// non-windowed fallback (tiers keep working even if ws is tiny)
__global__ __launch_bounds__(256) void fill_csr(const void* ei, int* cursor, int* csr,
                                                long long E, const int* flag) {
    long long e = (long long)blockIdx.x * 256 + threadIdx.x;
    if (e >= E) return;
    int is64 = *flag;
    int row = load_idx(ei, e, is64);
    int col = load_idx(ei, E + e, is64);
    int pos = atomicAdd(&cursor[col], 1);
    csr[pos] = row;
}

// ---------------------------------------------------------------------------
// layer GEMMs (tiny: vector-FP32; no fp32-input MFMA on CDNA4)
// ---------------------------------------------------------------------------
__global__ __launch_bounds__(256) void gemm1(const float* __restrict__ x,
                                             const float* __restrict__ W1,
                                             float* __restrict__ m1,
                                             __hip_bfloat16* __restrict__ m1b,
                                             int n, int bf16out) {
    __shared__ float sW[IN_CH * HID];     // 16 KB
    __shared__ float sx[8][IN_CH];        // 4 KB
    for (int i = threadIdx.x; i < IN_CH * HID; i += 256) sW[i] = W1[i];
    int g = threadIdx.x >> 5;
    int c = threadIdx.x & 31;
    long long node = (long long)blockIdx.x * 8 + g;
    bool active = node < n;
    if (active) {
        const float4* xr = (const float4*)(x + node * IN_CH);
        float4 v = xr[c];
        sx[g][c * 4 + 0] = v.x; sx[g][c * 4 + 1] = v.y;
        sx[g][c * 4 + 2] = v.z; sx[g][c * 4 + 3] = v.w;
    }
    __syncthreads();
    if (!active) return;
    float acc = 0.f;
#pragma unroll
    for (int k = 0; k < IN_CH; ++k)
        acc = fmaf(sx[g][k], sW[k * HID + c], acc);
    if (bf16out) m1b[node * HID + c] = __float2bfloat16(acc);
    else         m1[node * HID + c] = acc;
}

__global__ __launch_bounds__(256) void gemm2(const float* __restrict__ h,
                                             const float* __restrict__ W2,
                                             float* __restrict__ m2, int n) {
    __shared__ float sW[HID * OUT_CH];    // 512 floats, strided load (256 thr)
    for (int i = threadIdx.x; i < HID * OUT_CH; i += 256) sW[i] = W2[i];
    __syncthreads();
    long long t = (long long)blockIdx.x * 256 + threadIdx.x;
    long long node = t >> 4;
    int c = (int)(t & 15);
    if (node >= n) return;
    const float* hr = h + node * HID;
    float acc = 0.f;
#pragma unroll
    for (int k = 0; k < HID; ++k)
        acc = fmaf(hr[k], sW[k * OUT_CH + c], acc);
    m2[node * OUT_CH + c] = acc;
}

// ---------------------------------------------------------------------------
// Tier 1: gather aggregation (CSR), no float atomics
// ---------------------------------------------------------------------------
__global__ __launch_bounds__(256) void agg1(const float* __restrict__ m1,
                                            const int* __restrict__ csr,
                                            const int* __restrict__ offs,
                                            const float* __restrict__ dinv,
                                            const float* __restrict__ b1,
                                            float* __restrict__ h, int n) {
    int g = threadIdx.x >> 5;
    int c = threadIdx.x & 31;
    long long node = (long long)blockIdx.x * 8 + g;
    if (node >= n) return;
    float di = dinv[node];
    float acc = m1[node * HID + c] * di;   // self loop (second di applied at end)
    int s = offs[node], epos = offs[node + 1];
    for (; s + 1 < epos; s += 2) {
        int s0 = csr[s], s1 = csr[s + 1];
        float f0 = dinv[s0], f1 = dinv[s1];
        acc = fmaf(m1[(long long)s0 * HID + c], f0, acc);
        acc = fmaf(m1[(long long)s1 * HID + c], f1, acc);
    }
    if (s < epos) {
        int s0 = csr[s];
        acc = fmaf(m1[(long long)s0 * HID + c], dinv[s0], acc);
    }
    float v = acc * di + b1[c];
    h[node * HID + c] = v > 0.f ? v : 0.f;
}

__global__ __launch_bounds__(256) void agg2(const float* __restrict__ m2,
                                            const int* __restrict__ csr,
                                            const int* __restrict__ offs,
                                            const float* __restrict__ dinv,
                                            const float* __restrict__ b2,
                                            float* __restrict__ out, int n) {
    int g = threadIdx.x >> 4;
    int c = threadIdx.x & 15;
    long long node = (long long)blockIdx.x * 16 + g;
    if (node >= n) return;
    float di = dinv[node];
    float acc = m2[node * OUT_CH + c] * di;
    int s = offs[node], epos = offs[node + 1];
    for (; s + 1 < epos; s += 2) {
        int s0 = csr[s], s1 = csr[s + 1];
        float f0 = dinv[s0], f1 = dinv[s1];
        acc = fmaf(m2[(long long)s0 * OUT_CH + c], f0, acc);
        acc = fmaf(m2[(long long)s1 * OUT_CH + c], f1, acc);
    }
    if (s < epos) {
        int s0 = csr[s];
        acc = fmaf(m2[(long long)s0 * OUT_CH + c], dinv[s0], acc);
    }
    out[node * OUT_CH + c] = acc * di + b2[c];
}

// ---------------------------------------------------------------------------
// Tier 2/3: atomic scatter fallback (small workspace)
// ---------------------------------------------------------------------------
template <int BSRC>
__global__ __launch_bounds__(256) void scatter1(const float* __restrict__ m1,
                                                const __hip_bfloat16* __restrict__ m1b,
                                                const void* ei, const float* __restrict__ dinv,
                                                float* __restrict__ h,
                                                long long ecount, const int* flag) {
    long long e = (long long)blockIdx.x * 8 + (threadIdx.x >> 5);
    int c = threadIdx.x & 31;
    if (e >= ecount) return;
    int is64 = *flag;
    int row = load_idx(ei, e, is64);
    int col = load_idx(ei, ecount + e, is64);
    float nrm = dinv[row] * dinv[col];
    float v = BSRC ? __bfloat162float(m1b[(long long)row * HID + c])
                   : m1[(long long)row * HID + c];
    atomicAdd(&h[(long long)col * HID + c], v * nrm);
}

template <int BSRC>
__global__ __launch_bounds__(256) void fixup1(const float* __restrict__ m1,
                                              const __hip_bfloat16* __restrict__ m1b,
                                              const float* __restrict__ dinv,
                                              const float* __restrict__ b1,
                                              float* __restrict__ h, int n) {
    long long t = (long long)blockIdx.x * 256 + threadIdx.x;
    long long node = t >> 5; int c = (int)(t & 31);
    if (node >= n) return;
    float di = dinv[node];
    float self = BSRC ? __bfloat162float(m1b[node * HID + c]) : m1[node * HID + c];
    float v = h[node * HID + c] + self * di * di + b1[c];
    h[node * HID + c] = v > 0.f ? v : 0.f;
}

__global__ __launch_bounds__(256) void scatter2(const float* __restrict__ m2, const void* ei,
                                                const float* __restrict__ dinv,
                                                float* __restrict__ out,
                                                long long ecount, const int* flag) {
    long long e = (long long)blockIdx.x * 16 + (threadIdx.x >> 4);
    int c = threadIdx.x & 15;
    if (e >= ecount) return;
    int is64 = *flag;
    int row = load_idx(ei, e, is64);
    int col = load_idx(ei, ecount + e, is64);
    float nrm = dinv[row] * dinv[col];
    atomicAdd(&out[(long long)col * OUT_CH + c], m2[(long long)row * OUT_CH + c] * nrm);
}

__global__ __launch_bounds__(256) void fixup2(const float* __restrict__ m2,
                                              const float* __restrict__ dinv,
                                              const float* __restrict__ b2,
                                              float* __restrict__ out, int n) {
    long long t = (long long)blockIdx.x * 256 + threadIdx.x;
    long long node = t >> 4; int c = (int)(t & 15);
    if (node >= n) return;
    float di = dinv[node];
    out[node * OUT_CH + c] += m2[node * OUT_CH + c] * di * di + b2[c];
}

// ---------------------------------------------------------------------------
extern "C" void kernel_launch(void* const* d_in, const int* in_sizes, int n_in,
                              void* d_out, int out_size, void* d_ws, size_t ws_size,
                              hipStream_t stream) {
    const float* x  = (const float*)d_in[0];
    const void*  ei = d_in[1];
    const float* W1 = (const float*)d_in[2];
    const float* b1 = (const float*)d_in[3];
    const float* W2 = (const float*)d_in[4];
    const float* b2 = (const float*)d_in[5];
    float* out = (float*)d_out;

    const int n = in_sizes[0] / IN_CH;           // 100000
    const long long E = in_sizes[1] / 2;         // 6400000

    char* w = (char*)d_ws;
    size_t used = 0;
    auto carve = [&](size_t bytes) -> void* {
        void* p = (void*)(w + used);
        used += (bytes + 255) & ~(size_t)255;
        return p;
    };
    auto A = [](size_t b) -> size_t { return (b + 255) & ~(size_t)255; };

    int*   cnt     = (int*)carve((size_t)n * 4);          // degree counts, later cursor
    int*   offs    = (int*)carve((size_t)(n + 1) * 4);
    float* dinv    = (float*)carve((size_t)n * 4);
    int*   partial = (int*)carve(4096);
    int*   flag    = (int*)carve(256);
    const size_t base = used;

    const size_t needT1 = base + A((size_t)E * 4) + A((size_t)n * HID * 4) + A((size_t)n * HID * 4);
    const size_t needT2 = base + A((size_t)n * HID * 4) + A((size_t)n * HID * 4);
    const int tier = (ws_size >= needT1) ? 1 : ((ws_size >= needT2) ? 2 : 3);

    const int nblkN  = (n + 255) / 256;
    const int nblkEv = (int)((E + 256LL * EPT - 1) / (256LL * EPT));   // vectorized edge scan
    const int nblkE  = (int)((E + 255) / 256);
    const int nblkSc = (n + SCAN_CHUNK - 1) / SCAN_CHUNK;
    const int nblkH  = (int)(((long long)n * HID + 255) / 256);
    const int nblkO  = (int)(((long long)n * OUT_CH + 255) / 256);

    detect_dtype<<<1, 64, 0, stream>>>(ei, E, n, flag);
    zero_int<<<nblkN, 256, 0, stream>>>(cnt, n);
    count_edges<<<nblkEv, 256, 0, stream>>>(ei, cnt, E, flag);
    compute_dinv<<<nblkN, 256, 0, stream>>>(cnt, dinv, n);

    if (tier == 1) {
        int*   csr = (int*)carve((size_t)E * 4);
        float* m1  = (float*)carve((size_t)n * HID * 4);
        float* h   = (float*)carve((size_t)n * HID * 4);
        float* m2  = m1;   // m1 dead after agg1; reuse for m2

        scan_partial<<<nblkSc, 256, 0, stream>>>(cnt, partial, n);
        scan_serial<<<1, 64, 0, stream>>>(partial, offs, nblkSc, n);
        scan_final<<<nblkSc, 256, 0, stream>>>(cnt, partial, offs, n);
        copy_int<<<nblkN, 256, 0, stream>>>(offs, cnt, n);      // cnt becomes cursor

        const int npw = (n + FILL_K - 1) / FILL_K;
        fill_csr_win<<<nblkEv * FILL_K, 256, 0, stream>>>(ei, cnt, csr, E, flag,
                                                          nblkEv, npw, n);

        gemm1<<<(n + 7) / 8, 256, 0, stream>>>(x, W1, m1, (__hip_bfloat16*)nullptr, n, 0);
        agg1<<<(n + 7) / 8, 256, 0, stream>>>(m1, csr, offs, dinv, b1, h, n);
        gemm2<<<nblkO, 256, 0, stream>>>(h, W2, m2, n);
        agg2<<<(n + 15) / 16, 256, 0, stream>>>(m2, csr, offs, dinv, b2, out, n);
    } else if (tier == 2) {
        float* m1 = (float*)carve((size_t)n * HID * 4);
        float* h  = (float*)carve((size_t)n * HID * 4);
        float* m2 = m1;

        gemm1<<<(n + 7) / 8, 256, 0, stream>>>(x, W1, m1, (__hip_bfloat16*)nullptr, n, 0);
        zero_float<<<nblkH, 256, 0, stream>>>(h, (long long)n * HID);
        scatter1<0><<<(int)((E + 7) / 8), 256, 0, stream>>>(m1, nullptr, ei, dinv, h, E, flag);
        fixup1<0><<<nblkH, 256, 0, stream>>>(m1, nullptr, dinv, b1, h, n);
        gemm2<<<nblkO, 256, 0, stream>>>(h, W2, m2, n);
        zero_float<<<nblkO, 256, 0, stream>>>(out, (long long)n * OUT_CH);
        scatter2<<<(int)((E + 15) / 16), 256, 0, stream>>>(m2, ei, dinv, out, E, flag);
        fixup2<<<nblkO, 256, 0, stream>>>(m2, dinv, b2, out, n);
    } else {
        __hip_bfloat16* m1b = (__hip_bfloat16*)carve((size_t)n * HID * 2);
        float* h  = (float*)carve((size_t)n * HID * 4);
        float* m2 = (float*)m1b;   // n*16*4 == n*32*2 bytes; m1b dead after fixup1

        gemm1<<<(n + 7) / 8, 256, 0, stream>>>(x, W1, (float*)nullptr, m1b, n, 1);
        zero_float<<<nblkH, 256, 0, stream>>>(h, (long long)n * HID);
        scatter1<1><<<(int)((E + 7) / 8), 256, 0, stream>>>(nullptr, m1b, ei, dinv, h, E, flag);
        fixup1<1><<<nblkH, 256, 0, stream>>>(nullptr, m1b, dinv, b1, h, n);
        gemm2<<<nblkO, 256, 0, stream>>>(h, W2, m2, n);
        zero_float<<<nblkO, 256, 0, stream>>>(out, (long long)n * OUT_CH);
        scatter2<<<(int)((E + 15) / 16), 256, 0, stream>>>(m2, ei, dinv, out, E, flag);
        fixup2<<<nblkO, 256, 0, stream>>>(m2, dinv, b2, out, n);
    }
}

// Round 5
// 823.320 us; speedup vs baseline: 1.4692x; 1.1863x over previous
//
#include <hip/hip_runtime.h>
#include <hip/hip_bf16.h>

#define IN_CH 128
#define HID 32
#define OUT_CH 16
#define SCAN_CHUNK 1024
#define NXCD 8           // windows == XCDs; window = blockIdx % 8 (round-robin map)
#define EPT 4            // edges per thread in edge-scan kernels

typedef int vint4 __attribute__((ext_vector_type(4)));   // clang-native: OK for nontemporal builtins

// ---------------------------------------------------------------------------
// dtype sniffing: edge_index is int64 per the reference but may arrive int32.
// ---------------------------------------------------------------------------
__global__ void detect_dtype(const void* ei, long long ecount, int n, int* flag) {
    if (threadIdx.x == 0 && blockIdx.x == 0) {
        int is64 = 1;
        const long long* p = (const long long*)ei;
        long long st = ecount / 64; if (st < 1) st = 1;
        for (int j = 0; j < 64; ++j) {
            long long idx = (long long)j * st;
            if (idx >= ecount) break;
            long long v = p[idx];
            if (v < 0 || v >= n) { is64 = 0; break; }
        }
        *flag = is64;
    }
}

__device__ __forceinline__ int load_idx(const void* ei, long long i, int is64) {
    return is64 ? (int)((const long long*)ei)[i] : ((const int*)ei)[i];
}

// 4 consecutive indices, nontemporal (streaming scan; don't pollute L2)
__device__ __forceinline__ void load_idx4_nt(const void* ei, long long off, int is64,
                                             int* c) {
    if (is64) {
        const long long* p = (const long long*)ei + off;
        c[0] = (int)__builtin_nontemporal_load(p + 0);
        c[1] = (int)__builtin_nontemporal_load(p + 1);
        c[2] = (int)__builtin_nontemporal_load(p + 2);
        c[3] = (int)__builtin_nontemporal_load(p + 3);
    } else {
        vint4 v = __builtin_nontemporal_load((const vint4*)((const int*)ei + off));
        c[0] = v.x; c[1] = v.y; c[2] = v.z; c[3] = v.w;
    }
}

// ---------------------------------------------------------------------------
__global__ __launch_bounds__(256) void zero_int(int* p, int n) {
    int i = blockIdx.x * 256 + threadIdx.x;
    if (i < n) p[i] = 0;
}

__global__ __launch_bounds__(256) void zero_float(float* p, long long n) {
    long long i = (long long)blockIdx.x * 256 + threadIdx.x;
    if (i < n) p[i] = 0.f;
}

__global__ __launch_bounds__(256) void count_edges(const void* ei, int* cnt,
                                                   long long E, const int* flag) {
    long long e0 = ((long long)blockIdx.x * 256 + threadIdx.x) * EPT;
    if (e0 >= E) return;
    int is64 = *flag;
    if (e0 + EPT <= E) {
        int c[EPT];
        load_idx4_nt(ei, E + e0, is64, c);
#pragma unroll
        for (int j = 0; j < EPT; ++j) atomicAdd(&cnt[c[j]], 1);
    } else {
        for (long long e = e0; e < E; ++e)
            atomicAdd(&cnt[load_idx(ei, E + e, is64)], 1);
    }
}

__global__ __launch_bounds__(256) void compute_dinv(const int* cnt, float* dinv, int n) {
    int i = blockIdx.x * 256 + threadIdx.x;
    if (i < n) dinv[i] = 1.0f / sqrtf((float)(cnt[i] + 1));  // +1 self loop
}

// ---------------------------------------------------------------------------
// exclusive scan (3-phase) over cnt -> offs
// ---------------------------------------------------------------------------
__global__ __launch_bounds__(256) void scan_partial(const int* cnt, int* partial, int n) {
    __shared__ int sd[256];
    int base = blockIdx.x * SCAN_CHUNK;
    int s = 0;
    for (int j = threadIdx.x; j < SCAN_CHUNK; j += 256) {
        int i = base + j;
        if (i < n) s += cnt[i];
    }
    sd[threadIdx.x] = s;
    __syncthreads();
    for (int off = 128; off > 0; off >>= 1) {
        if (threadIdx.x < off) sd[threadIdx.x] += sd[threadIdx.x + off];
        __syncthreads();
    }
    if (threadIdx.x == 0) partial[blockIdx.x] = sd[0];
}

__global__ void scan_serial(int* partial, int* offs, int nblk, int n) {
    if (threadIdx.x == 0 && blockIdx.x == 0) {
        int run = 0;
        for (int b = 0; b < nblk; ++b) { int t = partial[b]; partial[b] = run; run += t; }
        offs[n] = run;
    }
}

__global__ __launch_bounds__(256) void scan_final(const int* cnt, const int* partial,
                                                  int* offs, int n) {
    __shared__ int sd[256];
    int base = blockIdx.x * SCAN_CHUNK;
    int t = threadIdx.x;
    int loc[4]; int ts = 0;
#pragma unroll
    for (int j = 0; j < 4; ++j) {
        int i = base + t * 4 + j;
        loc[j] = (i < n) ? cnt[i] : 0;
        ts += loc[j];
    }
    sd[t] = ts;
    __syncthreads();
    for (int off = 1; off < 256; off <<= 1) {
        int v = (t >= off) ? sd[t - off] : 0;
        __syncthreads();
        sd[t] += v;
        __syncthreads();
    }
    int excl = sd[t] - ts + partial[blockIdx.x];
#pragma unroll
    for (int j = 0; j < 4; ++j) {
        int i = base + t * 4 + j;
        if (i < n) offs[i] = excl;
        excl += loc[j];
    }
}

__global__ __launch_bounds__(256) void copy_int(const int* src, int* dst, int n) {
    int i = blockIdx.x * 256 + threadIdx.x;
    if (i < n) dst[i] = src[i];
}

// ---------------------------------------------------------------------------
// XCD-pinned windowed CSR fill: window = blockIdx % 8 matches the HW XCD
// round-robin, so each 3.2MB csr window is written from exactly ONE XCD's L2
// -> all 16 writes/line merge in that L2 before a single full-line writeback.
// Col re-scan uses nontemporal loads to keep the window resident.
// ---------------------------------------------------------------------------
__global__ __launch_bounds__(256) void fill_csr_win(const void* ei, int* cursor, int* csr,
                                                    long long E, const int* flag,
                                                    int npw, int n) {
    int w = blockIdx.x & (NXCD - 1);      // window == XCD (round-robin dispatch)
    int b = blockIdx.x >> 3;              // edge chunk
    int lo = w * npw;
    int hi = lo + npw; if (hi > n) hi = n;
    long long e0 = ((long long)b * 256 + threadIdx.x) * EPT;
    if (e0 >= E) return;
    int is64 = *flag;
    if (e0 + EPT <= E) {
        int c[EPT];
        load_idx4_nt(ei, E + e0, is64, c);
#pragma unroll
        for (int j = 0; j < EPT; ++j) {
            if (c[j] >= lo && c[j] < hi) {
                int row = load_idx(ei, e0 + j, is64);
                int pos = atomicAdd(&cursor[c[j]], 1);
                csr[pos] = row;
            }
        }
    } else {
        for (long long e = e0; e < E; ++e) {
            int col = load_idx(ei, E + e, is64);
            if (col >= lo && col < hi) {
                int row = load_idx(ei, e, is64);
                int pos = atomicAdd(&cursor[col], 1);
                csr[pos] = row;
            }
        }
    }
}

// ---------------------------------------------------------------------------
// layer GEMMs (tiny: vector-FP32; no fp32-input MFMA on CDNA4)
// ---------------------------------------------------------------------------
__global__ __launch_bounds__(256) void gemm1(const float* __restrict__ x,
                                             const float* __restrict__ W1,
                                             float* __restrict__ m1,
                                             __hip_bfloat16* __restrict__ m1b,
                                             int n, int bf16out) {
    __shared__ float sW[IN_CH * HID];     // 16 KB
    __shared__ float sx[8][IN_CH];        // 4 KB
    for (int i = threadIdx.x; i < IN_CH * HID; i += 256) sW[i] = W1[i];
    int g = threadIdx.x >> 5;
    int c = threadIdx.x & 31;
    long long node = (long long)blockIdx.x * 8 + g;
    bool active = node < n;
    if (active) {
        const float4* xr = (const float4*)(x + node * IN_CH);
        float4 v = xr[c];
        sx[g][c * 4 + 0] = v.x; sx[g][c * 4 + 1] = v.y;
        sx[g][c * 4 + 2] = v.z; sx[g][c * 4 + 3] = v.w;
    }
    __syncthreads();
    if (!active) return;
    float acc = 0.f;
#pragma unroll
    for (int k = 0; k < IN_CH; ++k)
        acc = fmaf(sx[g][k], sW[k * HID + c], acc);
    if (bf16out) m1b[node * HID + c] = __float2bfloat16(acc);
    else         m1[node * HID + c] = acc;
}

__global__ __launch_bounds__(256) void gemm2(const float* __restrict__ h,
                                             const float* __restrict__ W2,
                                             float* __restrict__ m2, int n) {
    __shared__ float sW[HID * OUT_CH];    // 512 floats, strided load (256 thr)
    for (int i = threadIdx.x; i < HID * OUT_CH; i += 256) sW[i] = W2[i];
    __syncthreads();
    long long t = (long long)blockIdx.x * 256 + threadIdx.x;
    long long node = t >> 4;
    int c = (int)(t & 15);
    if (node >= n) return;
    const float* hr = h + node * HID;
    float acc = 0.f;
#pragma unroll
    for (int k = 0; k < HID; ++k)
        acc = fmaf(hr[k], sW[k * OUT_CH + c], acc);
    m2[node * OUT_CH + c] = acc;
}

// ---------------------------------------------------------------------------
// Tier 1: gather aggregation (CSR), no float atomics; 4-wide unrolled gather
// ---------------------------------------------------------------------------
__global__ __launch_bounds__(256) void agg1(const float* __restrict__ m1,
                                            const int* __restrict__ csr,
                                            const int* __restrict__ offs,
                                            const float* __restrict__ dinv,
                                            const float* __restrict__ b1,
                                            float* __restrict__ h, int n) {
    int g = threadIdx.x >> 5;
    int c = threadIdx.x & 31;
    long long node = (long long)blockIdx.x * 8 + g;
    if (node >= n) return;
    float di = dinv[node];
    float acc = m1[node * HID + c] * di;   // self loop (second di applied at end)
    int s = offs[node], epos = offs[node + 1];
    for (; s + 3 < epos; s += 4) {
        int s0 = csr[s], s1 = csr[s + 1], s2 = csr[s + 2], s3 = csr[s + 3];
        float f0 = dinv[s0], f1 = dinv[s1], f2 = dinv[s2], f3 = dinv[s3];
        float v0 = m1[(long long)s0 * HID + c];
        float v1 = m1[(long long)s1 * HID + c];
        float v2 = m1[(long long)s2 * HID + c];
        float v3 = m1[(long long)s3 * HID + c];
        acc = fmaf(v0, f0, acc);
        acc = fmaf(v1, f1, acc);
        acc = fmaf(v2, f2, acc);
        acc = fmaf(v3, f3, acc);
    }
    for (; s < epos; ++s) {
        int s0 = csr[s];
        acc = fmaf(m1[(long long)s0 * HID + c], dinv[s0], acc);
    }
    float v = acc * di + b1[c];
    h[node * HID + c] = v > 0.f ? v : 0.f;
}

__global__ __launch_bounds__(256) void agg2(const float* __restrict__ m2,
                                            const int* __restrict__ csr,
                                            const int* __restrict__ offs,
                                            const float* __restrict__ dinv,
                                            const float* __restrict__ b2,
                                            float* __restrict__ out, int n) {
    int g = threadIdx.x >> 4;
    int c = threadIdx.x & 15;
    long long node = (long long)blockIdx.x * 16 + g;
    if (node >= n) return;
    float di = dinv[node];
    float acc = m2[node * OUT_CH + c] * di;
    int s = offs[node], epos = offs[node + 1];
    for (; s + 3 < epos; s += 4) {
        int s0 = csr[s], s1 = csr[s + 1], s2 = csr[s + 2], s3 = csr[s + 3];
        float f0 = dinv[s0], f1 = dinv[s1], f2 = dinv[s2], f3 = dinv[s3];
        float v0 = m2[(long long)s0 * OUT_CH + c];
        float v1 = m2[(long long)s1 * OUT_CH + c];
        float v2 = m2[(long long)s2 * OUT_CH + c];
        float v3 = m2[(long long)s3 * OUT_CH + c];
        acc = fmaf(v0, f0, acc);
        acc = fmaf(v1, f1, acc);
        acc = fmaf(v2, f2, acc);
        acc = fmaf(v3, f3, acc);
    }
    for (; s < epos; ++s) {
        int s0 = csr[s];
        acc = fmaf(m2[(long long)s0 * OUT_CH + c], dinv[s0], acc);
    }
    out[node * OUT_CH + c] = acc * di + b2[c];
}

// ---------------------------------------------------------------------------
// Tier 2/3: atomic scatter fallback (small workspace)
// ---------------------------------------------------------------------------
template <int BSRC>
__global__ __launch_bounds__(256) void scatter1(const float* __restrict__ m1,
                                                const __hip_bfloat16* __restrict__ m1b,
                                                const void* ei, const float* __restrict__ dinv,
                                                float* __restrict__ h,
                                                long long ecount, const int* flag) {
    long long e = (long long)blockIdx.x * 8 + (threadIdx.x >> 5);
    int c = threadIdx.x & 31;
    if (e >= ecount) return;
    int is64 = *flag;
    int row = load_idx(ei, e, is64);
    int col = load_idx(ei, ecount + e, is64);
    float nrm = dinv[row] * dinv[col];
    float v = BSRC ? __bfloat162float(m1b[(long long)row * HID + c])
                   : m1[(long long)row * HID + c];
    atomicAdd(&h[(long long)col * HID + c], v * nrm);
}

template <int BSRC>
__global__ __launch_bounds__(256) void fixup1(const float* __restrict__ m1,
                                              const __hip_bfloat16* __restrict__ m1b,
                                              const float* __restrict__ dinv,
                                              const float* __restrict__ b1,
                                              float* __restrict__ h, int n) {
    long long t = (long long)blockIdx.x * 256 + threadIdx.x;
    long long node = t >> 5; int c = (int)(t & 31);
    if (node >= n) return;
    float di = dinv[node];
    float self = BSRC ? __bfloat162float(m1b[node * HID + c]) : m1[node * HID + c];
    float v = h[node * HID + c] + self * di * di + b1[c];
    h[node * HID + c] = v > 0.f ? v : 0.f;
}

__global__ __launch_bounds__(256) void scatter2(const float* __restrict__ m2, const void* ei,
                                                const float* __restrict__ dinv,
                                                float* __restrict__ out,
                                                long long ecount, const int* flag) {
    long long e = (long long)blockIdx.x * 16 + (threadIdx.x >> 4);
    int c = threadIdx.x & 15;
    if (e >= ecount) return;
    int is64 = *flag;
    int row = load_idx(ei, e, is64);
    int col = load_idx(ei, ecount + e, is64);
    float nrm = dinv[row] * dinv[col];
    atomicAdd(&out[(long long)col * OUT_CH + c], m2[(long long)row * OUT_CH + c] * nrm);
}

__global__ __launch_bounds__(256) void fixup2(const float* __restrict__ m2,
                                              const float* __restrict__ dinv,
                                              const float* __restrict__ b2,
                                              float* __restrict__ out, int n) {
    long long t = (long long)blockIdx.x * 256 + threadIdx.x;
    long long node = t >> 4; int c = (int)(t & 15);
    if (node >= n) return;
    float di = dinv[node];
    out[node * OUT_CH + c] += m2[node * OUT_CH + c] * di * di + b2[c];
}

// ---------------------------------------------------------------------------
extern "C" void kernel_launch(void* const* d_in, const int* in_sizes, int n_in,
                              void* d_out, int out_size, void* d_ws, size_t ws_size,
                              hipStream_t stream) {
    const float* x  = (const float*)d_in[0];
    const void*  ei = d_in[1];
    const float* W1 = (const float*)d_in[2];
    const float* b1 = (const float*)d_in[3];
    const float* W2 = (const float*)d_in[4];
    const float* b2 = (const float*)d_in[5];
    float* out = (float*)d_out;

    const int n = in_sizes[0] / IN_CH;           // 100000
    const long long E = in_sizes[1] / 2;         // 6400000

    char* w = (char*)d_ws;
    size_t used = 0;
    auto carve = [&](size_t bytes) -> void* {
        void* p = (void*)(w + used);
        used += (bytes + 255) & ~(size_t)255;
        return p;
    };
    auto A = [](size_t b) -> size_t { return (b + 255) & ~(size_t)255; };

    int*   cnt     = (int*)carve((size_t)n * 4);          // degree counts, later cursor
    int*   offs    = (int*)carve((size_t)(n + 1) * 4);
    float* dinv    = (float*)carve((size_t)n * 4);
    int*   partial = (int*)carve(4096);
    int*   flag    = (int*)carve(256);
    const size_t base = used;

    const size_t needT1 = base + A((size_t)E * 4) + A((size_t)n * HID * 4) + A((size_t)n * HID * 4);
    const size_t needT2 = base + A((size_t)n * HID * 4) + A((size_t)n * HID * 4);
    const int tier = (ws_size >= needT1) ? 1 : ((ws_size >= needT2) ? 2 : 3);

    const int nblkN  = (n + 255) / 256;
    const int nblkEv = (int)((E + 256LL * EPT - 1) / (256LL * EPT));   // vectorized edge scan
    const int nblkSc = (n + SCAN_CHUNK - 1) / SCAN_CHUNK;
    const int nblkH  = (int)(((long long)n * HID + 255) / 256);
    const int nblkO  = (int)(((long long)n * OUT_CH + 255) / 256);

    detect_dtype<<<1, 64, 0, stream>>>(ei, E, n, flag);
    zero_int<<<nblkN, 256, 0, stream>>>(cnt, n);
    count_edges<<<nblkEv, 256, 0, stream>>>(ei, cnt, E, flag);
    compute_dinv<<<nblkN, 256, 0, stream>>>(cnt, dinv, n);

    if (tier == 1) {
        int*   csr = (int*)carve((size_t)E * 4);
        float* m1  = (float*)carve((size_t)n * HID * 4);
        float* h   = (float*)carve((size_t)n * HID * 4);
        float* m2  = m1;   // m1 dead after agg1; reuse for m2

        scan_partial<<<nblkSc, 256, 0, stream>>>(cnt, partial, n);
        scan_serial<<<1, 64, 0, stream>>>(partial, offs, nblkSc, n);
        scan_final<<<nblkSc, 256, 0, stream>>>(cnt, partial, offs, n);
        copy_int<<<nblkN, 256, 0, stream>>>(offs, cnt, n);      // cnt becomes cursor

        const int npw = (n + NXCD - 1) / NXCD;
        fill_csr_win<<<nblkEv * NXCD, 256, 0, stream>>>(ei, cnt, csr, E, flag, npw, n);

        gemm1<<<(n + 7) / 8, 256, 0, stream>>>(x, W1, m1, (__hip_bfloat16*)nullptr, n, 0);
        agg1<<<(n + 7) / 8, 256, 0, stream>>>(m1, csr, offs, dinv, b1, h, n);
        gemm2<<<nblkO, 256, 0, stream>>>(h, W2, m2, n);
        agg2<<<(n + 15) / 16, 256, 0, stream>>>(m2, csr, offs, dinv, b2, out, n);
    } else if (tier == 2) {
        float* m1 = (float*)carve((size_t)n * HID * 4);
        float* h  = (float*)carve((size_t)n * HID * 4);
        float* m2 = m1;

        gemm1<<<(n + 7) / 8, 256, 0, stream>>>(x, W1, m1, (__hip_bfloat16*)nullptr, n, 0);
        zero_float<<<nblkH, 256, 0, stream>>>(h, (long long)n * HID);
        scatter1<0><<<(int)((E + 7) / 8), 256, 0, stream>>>(m1, nullptr, ei, dinv, h, E, flag);
        fixup1<0><<<nblkH, 256, 0, stream>>>(m1, nullptr, dinv, b1, h, n);
        gemm2<<<nblkO, 256, 0, stream>>>(h, W2, m2, n);
        zero_float<<<nblkO, 256, 0, stream>>>(out, (long long)n * OUT_CH);
        scatter2<<<(int)((E + 15) / 16), 256, 0, stream>>>(m2, ei, dinv, out, E, flag);
        fixup2<<<nblkO, 256, 0, stream>>>(m2, dinv, b2, out, n);
    } else {
        __hip_bfloat16* m1b = (__hip_bfloat16*)carve((size_t)n * HID * 2);
        float* h  = (float*)carve((size_t)n * HID * 4);
        float* m2 = (float*)m1b;   // n*16*4 == n*32*2 bytes; m1b dead after fixup1

        gemm1<<<(n + 7) / 8, 256, 0, stream>>>(x, W1, (float*)nullptr, m1b, n, 1);
        zero_float<<<nblkH, 256, 0, stream>>>(h, (long long)n * HID);
        scatter1<1><<<(int)((E + 7) / 8), 256, 0, stream>>>(nullptr, m1b, ei, dinv, h, E, flag);
        fixup1<1><<<nblkH, 256, 0, stream>>>(nullptr, m1b, dinv, b1, h, n);
        gemm2<<<nblkO, 256, 0, stream>>>(h, W2, m2, n);
        zero_float<<<nblkO, 256, 0, stream>>>(out, (long long)n * OUT_CH);
        scatter2<<<(int)((E + 15) / 16), 256, 0, stream>>>(m2, ei, dinv, out, E, flag);
        fixup2<<<nblkO, 256, 0, stream>>>(m2, dinv, b2, out, n);
    }
}